// Round 5
// baseline (13630.501 us; speedup 1.0000x reference)
//
#include <hip/hip_runtime.h>

#define NB 64
#define NNODE 1085
#define HIST 24
#define PRED 24
#define KHOP 3
#define HDIM 64
#define FXD 1
#define FMD 11
#define FD 12
#define NE 17360
#define NROWS (NB*NNODE)   // 69440
#define WPAR 1024          // waves per t-slice in gather partition

// Layout: node tensors are (t, n, f, b) : addr = ((t*NNODE + n)*FD + f)*64 + b
// row-major rows are row = n*64 + b. h is (k, row, HDIM).

typedef float v4 __attribute__((ext_vector_type(4)));

__device__ __forceinline__ float sigm(float x){ return 1.0f/(1.0f + __expf(-x)); }
__device__ __forceinline__ float tanh_f(float x){ return 1.0f - 2.0f/(__expf(2.0f*x)+1.0f); }

// ---------------- CSR build (once per launch) ----------------
__global__ void csr_count_k(const int* __restrict__ dst, int* __restrict__ deg)
{
    int e = blockIdx.x*256 + threadIdx.x;
    if (e < NE) atomicAdd(&deg[dst[e]], 1);
}

__global__ __launch_bounds__(1024) void csr_scan_k(const int* __restrict__ deg,
                                                   int* __restrict__ offs, int* __restrict__ curs)
{
    __shared__ int s[2][2048];
    int t = threadIdx.x;
    for (int i=t;i<2048;i+=1024) s[0][i] = (i<NNODE) ? deg[i] : 0;
    __syncthreads();
    int cur = 0;
    for (int d=1; d<2048; d<<=1){
        for (int i=t;i<2048;i+=1024){
            int v = s[cur][i];
            if (i>=d) v += s[cur][i-d];
            s[cur^1][i] = v;
        }
        __syncthreads();
        cur ^= 1;
    }
    for (int i=t;i<=NNODE;i+=1024){
        int v = (i==0) ? 0 : s[cur][i-1];
        offs[i] = v;
        if (i<NNODE) curs[i] = v;
    }
}

// store SRC node id directly in CSR slot (dst is implicit = bucket node)
__global__ void csr_fill_k(const int* __restrict__ dst, const int* __restrict__ src,
                           int* __restrict__ curs, int* __restrict__ esrc)
{
    int e = blockIdx.x*256 + threadIdx.x;
    if (e < NE){
        int d = dst[e];
        int p = atomicAdd(&curs[d], 1);
        esrc[p] = src[e];
    }
}

// degree-balanced wave->node-range partition: wpart[w] = lower_bound(offs, w*NE/WPAR)
__global__ void csr_part_k(const int* __restrict__ offs, int* __restrict__ wpart)
{
    int w = blockIdx.x*256 + threadIdx.x;
    if (w > WPAR) return;
    if (w == 0)    { wpart[0] = 0;        return; }
    if (w == WPAR) { wpart[WPAR] = NNODE; return; }
    int target = (int)(((long)w * NE) / WPAR);
    int lo = 0, hi = NNODE;
    while (lo < hi){ int mid = (lo+hi)>>1; if (offs[mid] >= target) hi = mid; else lo = mid+1; }
    wpart[w] = lo;
}

// ---------------- hist-phase batched feature build ----------------
// xn_all slice ti: (n,f,b); reads x_hist[b,t0+ti,n] and enc_misc[b,t0+ti+1,n,:]
__global__ void build_hist_k(const float* __restrict__ x_hist, const float* __restrict__ enc_misc,
                             int t0, int T, float* __restrict__ xn_all)
{
    long idx = (long)blockIdx.x*256 + threadIdx.x;
    if (idx >= (long)T*NROWS) return;
    int b = (int)(idx & 63);
    long nn = idx >> 6;
    int ti = (int)(nn / NNODE);
    int n  = (int)(nn - (long)ti*NNODE);
    int t  = t0 + ti;
    float* xp = xn_all + (long)ti*NROWS*FD + (long)n*FD*64 + b;
    xp[0] = x_hist[((long)b*HIST + t)*NNODE + n];
    const float* fp = enc_misc + (((long)b*HIST + (t+1))*NNODE + n)*FMD;
    #pragma unroll
    for (int i=0;i<FMD;i++) xp[(1+i)*64] = fp[i];
}

// ---------------- single-step feature build (pred phase) ----------------
__global__ void build_xn_k(const float* __restrict__ xsrc, int from_xcur,
                           const float* __restrict__ dec, int p,
                           float* __restrict__ xn)
{
    int idx = blockIdx.x*256 + threadIdx.x;
    if (idx >= NROWS) return;
    int b = idx & 63, n = idx >> 6;
    float v0 = from_xcur ? xsrc[idx]
                         : xsrc[((long)b*HIST + (HIST-1))*NNODE + n];
    float* xp = xn + (long)n*FD*64 + b;
    xp[0] = v0;
    const float* fp = dec + (((long)b*PRED + p)*NNODE + n)*FMD;
    #pragma unroll
    for (int i=0;i<FMD;i++) xp[(1+i)*64] = fp[i];
}

// ---------------- GNN hop: lane=batch, wave=node-range, no atomics ----------------
__global__ __launch_bounds__(256) void gnn_gather_k(const float* __restrict__ xin,
    const float* __restrict__ We, const float* __restrict__ be,
    const int* __restrict__ esrc, const int* __restrict__ offs,
    const int* __restrict__ wpart, float* __restrict__ xout)
{
    __shared__ float w_s[288];
    __shared__ float be_s[12];
    const int tid = threadIdx.x;
    for (int i=tid;i<288;i+=256) w_s[i]=We[i];
    if (tid<12) be_s[tid]=be[tid];
    __syncthreads();

    const int lane = tid & 63;
    const int wave = (blockIdx.x*256 + tid) >> 6;     // 0..WPAR-1
    const long sbase = (long)blockIdx.y * ((long)NROWS*FD);
    const float* x = xin + sbase;
    float* xo = xout + sbase;

    const int n0 = wpart[wave], n1 = wpart[wave+1];
    for (int n=n0; n<n1; ++n){
        float xd[12], part[12], acc[12];
        const float* xb = x + (long)n*768 + lane;
        #pragma unroll
        for (int f=0;f<12;f++) xd[f] = xb[f*64];
        #pragma unroll
        for (int f=0;f<12;f++){ part[f]=be_s[f]; acc[f]=0.f; }
        #pragma unroll
        for (int f=0;f<12;f++){
            float xv = xd[f];
            const float* wrow = &w_s[(12+f)*12];
            #pragma unroll
            for (int j=0;j<12;j++) part[j] += xv*wrow[j];
        }
        const int e0 = offs[n], e1 = offs[n+1];
        for (int idx=e0; idx<e1; ++idx){
            int s = esrc[idx];                         // wave-uniform -> scalar load
            const float* xsb = x + (long)s*768 + lane;
            float m[12];
            #pragma unroll
            for (int f=0;f<12;f++) m[f]=part[f];
            #pragma unroll
            for (int f=0;f<12;f++){
                float xv = xsb[f*64];
                const float* wrow = &w_s[f*12];
                #pragma unroll
                for (int j=0;j<12;j++) m[j] += xv*wrow[j];
            }
            #pragma unroll
            for (int f=0;f<12;f++) acc[f] += fmaxf(m[f],0.f);
        }
        float* xob = xo + (long)n*768 + lane;
        #pragma unroll
        for (int f=0;f<12;f++) xob[f*64] = xd[f] + acc[f];
    }
}

// ---------------- Fused GRU over 3 hops (blockIdx.y = k), tile = one node ----------------
#define KC 44
__global__ __launch_bounds__(256) void gru3_k(
    const float* __restrict__ xg_base, long k_stride,
    const float* __restrict__ xn,
    float* __restrict__ h_base,
    const float* __restrict__ Wx, const float* __restrict__ Wh,
    const float* __restrict__ bx, const float* __restrict__ bh)
{
    const int k = blockIdx.y;
    const int n = blockIdx.x;
    const float* xgn = xg_base + (long)k*k_stride + (long)n*768;
    const float* xnn = xn + (long)n*768;
    float*       hn  = h_base + ((size_t)k*NROWS + (long)n*64)*HDIM;
    const float* wx  = Wx + (size_t)k*24*192;
    const float* wh  = Wh + (size_t)k*64*192;
    const float* bxk = bx + k*192;
    const float* bhk = bh + k*192;

    __shared__ __align__(16) float A_s[KC][64];
    __shared__ __align__(16) float W_s[KC][192];
    const int tid = threadIdx.x;
    const int tx = tid & 15, ty = tid >> 4;

    const v4* wx4 = (const v4*)wx;
    const v4* wh4 = (const v4*)wh;
    const v4* h4  = (const v4*)hn;

    float acc_r[16], acc_z[16], acc_gn[16], acc_ghn[16];
    #pragma unroll
    for (int i=0;i<16;i++){ acc_r[i]=0.f; acc_z[i]=0.f; acc_gn[i]=0.f; acc_ghn[i]=0.f; }

    // ---- chunk 0: A rows 0..11 = xg (contig copy), 12..23 = xn, 24..43 = h cols 0..19 ----
    for (int i=tid; i<KC*48; i+=256){
        int kk = i/48, q = i - kk*48;
        v4 w = (kk<24) ? wx4[kk*48+q] : wh4[(kk-24)*48+q];
        *(v4*)&W_s[kk][q*4] = w;
    }
    for (int i=tid; i<192; i+=256) ((v4*)A_s)[i]       = ((const v4*)xgn)[i];
    for (int i=tid; i<192; i+=256) ((v4*)A_s)[192+i]   = ((const v4*)xnn)[i];
    for (int i=tid; i<320; i+=256){
        int r = i/5, q = i - r*5;
        v4 v = h4[r*16+q];
        #pragma unroll
        for (int j=0;j<4;j++) A_s[24+4*q+j][r] = v[j];
    }
    __syncthreads();
    #pragma unroll 4
    for (int kk=0;kk<24;kk++){
        v4 av=*(const v4*)&A_s[kk][ty*4];
        v4 wr=*(const v4*)&W_s[kk][tx*4];
        v4 wz=*(const v4*)&W_s[kk][64+tx*4];
        v4 wn=*(const v4*)&W_s[kk][128+tx*4];
        #pragma unroll
        for (int dr=0;dr<4;dr++)
            #pragma unroll
            for (int dc=0;dc<4;dc++){
                acc_r[dr*4+dc]+=av[dr]*wr[dc];
                acc_z[dr*4+dc]+=av[dr]*wz[dc];
                acc_gn[dr*4+dc]+=av[dr]*wn[dc];
            }
    }
    #pragma unroll 4
    for (int kk=24;kk<44;kk++){
        v4 av=*(const v4*)&A_s[kk][ty*4];
        v4 wr=*(const v4*)&W_s[kk][tx*4];
        v4 wz=*(const v4*)&W_s[kk][64+tx*4];
        v4 wn=*(const v4*)&W_s[kk][128+tx*4];
        #pragma unroll
        for (int dr=0;dr<4;dr++)
            #pragma unroll
            for (int dc=0;dc<4;dc++){
                acc_r[dr*4+dc]+=av[dr]*wr[dc];
                acc_z[dr*4+dc]+=av[dr]*wz[dc];
                acc_ghn[dr*4+dc]+=av[dr]*wn[dc];
            }
    }
    __syncthreads();
    // ---- chunk 1: A rows 0..43 = h cols 20..63 ----
    for (int i=tid; i<KC*48; i+=256){
        int kk = i/48, q = i - kk*48;
        *(v4*)&W_s[kk][q*4] = wh4[(20+kk)*48+q];
    }
    for (int i=tid; i<704; i+=256){
        int r = i/11, q = i - r*11;
        v4 v = h4[r*16+5+q];
        #pragma unroll
        for (int j=0;j<4;j++) A_s[4*q+j][r] = v[j];
    }
    __syncthreads();
    #pragma unroll 4
    for (int kk=0;kk<44;kk++){
        v4 av=*(const v4*)&A_s[kk][ty*4];
        v4 wr=*(const v4*)&W_s[kk][tx*4];
        v4 wz=*(const v4*)&W_s[kk][64+tx*4];
        v4 wn=*(const v4*)&W_s[kk][128+tx*4];
        #pragma unroll
        for (int dr=0;dr<4;dr++)
            #pragma unroll
            for (int dc=0;dc<4;dc++){
                acc_r[dr*4+dc]+=av[dr]*wr[dc];
                acc_z[dr*4+dc]+=av[dr]*wz[dc];
                acc_ghn[dr*4+dc]+=av[dr]*wn[dc];
            }
    }

    // ---- epilogue ----
    v4 bxr=*(const v4*)&bxk[tx*4],     bhr=*(const v4*)&bhk[tx*4];
    v4 bxz=*(const v4*)&bxk[64+tx*4],  bhz=*(const v4*)&bhk[64+tx*4];
    v4 bxn=*(const v4*)&bxk[128+tx*4], bhn=*(const v4*)&bhk[128+tx*4];
    #pragma unroll
    for (int dr=0;dr<4;dr++){
        int lr = ty*4 + dr;
        v4 hold = *(const v4*)&hn[lr*HDIM + tx*4];
        v4 hnew;
        #pragma unroll
        for (int dc=0;dc<4;dc++){
            float rr = sigm(acc_r[dr*4+dc] + bxr[dc] + bhr[dc]);
            float zz = sigm(acc_z[dr*4+dc] + bxz[dc] + bhz[dc]);
            float nn = tanh_f(acc_gn[dr*4+dc] + bxn[dc] + rr*(acc_ghn[dr*4+dc] + bhn[dc]));
            hnew[dc] = (1.0f-zz)*nn + zz*hold[dc];
        }
        *(v4*)&hn[lr*HDIM + tx*4] = hnew;
    }
}

// ---------------- fc ----------------
__global__ void fc_k(const float* __restrict__ h, const float* __restrict__ fc_w,
                     const float* __restrict__ fc_b, float* __restrict__ x_cur,
                     float* __restrict__ out, int p)
{
    int idx = blockIdx.x*256+threadIdx.x;
    if (idx>=NROWS) return;
    float acc = fc_b[0];
    #pragma unroll
    for (int k=0;k<3;k++){
        const float* hb = h + ((size_t)k*NROWS + idx)*HDIM;
        const float* wb = fc_w + k*HDIM;
        #pragma unroll
        for (int q=0;q<16;q++){
            v4 hv=*(const v4*)&hb[q*4];
            v4 wv=*(const v4*)&wb[q*4];
            acc += hv[0]*wv[0]+hv[1]*wv[1]+hv[2]*wv[2]+hv[3]*wv[3];
        }
    }
    x_cur[idx]=acc;
    int b = idx & 63, n = idx >> 6;
    out[((long)b*PRED + p)*NNODE + n] = acc;
}

extern "C" void kernel_launch(void* const* d_in, const int* in_sizes, int n_in,
                              void* d_out, int out_size, void* d_ws, size_t ws_size,
                              hipStream_t stream)
{
    const float* x_hist   = (const float*)d_in[0];
    const float* enc_misc = (const float*)d_in[1];
    const float* dec      = (const float*)d_in[2];
    const float* We       = (const float*)d_in[3];
    const float* be       = (const float*)d_in[4];
    const float* Wx       = (const float*)d_in[5];
    const float* Wh       = (const float*)d_in[6];
    const float* bx       = (const float*)d_in[7];
    const float* bh       = (const float*)d_in[8];
    const float* fc_w     = (const float*)d_in[9];
    const float* fc_b     = (const float*)d_in[10];
    const int*   src      = (const int*)d_in[11];
    const int*   dst      = (const int*)d_in[12];
    float* out = (float*)d_out;

    // ---- workspace layout (dynamic hist-batch chunk) ----
    const size_t SZ_T = (size_t)NROWS*FD;               // one t-slice: 833,280 floats
    size_t fixed_f = (size_t)3*NROWS*HDIM + NROWS + 64*1024;
    size_t avail_f = ws_size/4;
    long tc = 1;
    if (avail_f > fixed_f + 4*SZ_T)
        tc = (long)((avail_f - fixed_f) / (4*SZ_T));
    if (tc > HIST-1) tc = HIST-1;
    if (tc < 1) tc = 1;
    const long T_CHUNK = tc;

    float* h      = (float*)d_ws;                       // 3*NROWS*HDIM
    float* x_cur  = h + (size_t)3*NROWS*HDIM;           // NROWS
    int*   deg    = (int*)(x_cur + NROWS);              // NNODE
    int*   offs   = deg + NNODE;                        // NNODE+1
    int*   curs   = offs + NNODE + 1;                   // NNODE
    int*   wpart  = curs + NNODE;                       // WPAR+1
    int*   esrc   = wpart + WPAR + 1;                   // NE
    float* xn_all = (float*)(esrc + NE) + 16;
    xn_all = (float*)(((size_t)xn_all + 255) & ~(size_t)255);
    float* xg_all = xn_all + T_CHUNK*SZ_T;              // 3 * T_CHUNK * SZ_T
    const long K_STRIDE = T_CHUNK*SZ_T;

    hipMemsetAsync(h, 0, (size_t)3*NROWS*HDIM*sizeof(float), stream);
    hipMemsetAsync(deg, 0, NNODE*sizeof(int), stream);

    const int gE = (NE+255)/256;
    csr_count_k<<<gE,256,0,stream>>>(dst, deg);
    csr_scan_k<<<1,1024,0,stream>>>(deg, offs, curs);
    csr_fill_k<<<gE,256,0,stream>>>(dst, src, curs, esrc);
    csr_part_k<<<(WPAR+256)/256,256,0,stream>>>(offs, wpart);

    const int gRow = (NROWS+255)/256;     // 272
    const int gGx  = WPAR*64/256;         // 256 blocks per t-slice

    // ---------------- history phase (batched GNN, sequential GRU) ----------------
    for (int t0 = 0; t0 < HIST-1; t0 += (int)T_CHUNK){
        int T = min((int)T_CHUNK, HIST-1-t0);
        build_hist_k<<<(int)(((long)T*NROWS+255)/256),256,0,stream>>>(x_hist, enc_misc, t0, T, xn_all);
        dim3 gG(gGx, T);
        gnn_gather_k<<<gG,256,0,stream>>>(xn_all,            We,be,esrc,offs,wpart, xg_all);
        gnn_gather_k<<<gG,256,0,stream>>>(xg_all,            We,be,esrc,offs,wpart, xg_all+K_STRIDE);
        gnn_gather_k<<<gG,256,0,stream>>>(xg_all+K_STRIDE,   We,be,esrc,offs,wpart, xg_all+2*K_STRIDE);
        for (int ti=0; ti<T; ti++){
            dim3 gU(NNODE, 3);
            gru3_k<<<gU,256,0,stream>>>(xg_all + ti*SZ_T, K_STRIDE,
                                        xn_all + ti*SZ_T, h, Wx, Wh, bx, bh);
        }
    }

    // ---------------- prediction phase (sequential) ----------------
    for (int p=0;p<PRED;p++){
        if (p==0)
            build_xn_k<<<gRow,256,0,stream>>>(x_hist, 0, dec, p, xn_all);
        else
            build_xn_k<<<gRow,256,0,stream>>>(x_cur, 1, dec, p, xn_all);
        dim3 gG(gGx, 1);
        gnn_gather_k<<<gG,256,0,stream>>>(xn_all,          We,be,esrc,offs,wpart, xg_all);
        gnn_gather_k<<<gG,256,0,stream>>>(xg_all,          We,be,esrc,offs,wpart, xg_all+K_STRIDE);
        gnn_gather_k<<<gG,256,0,stream>>>(xg_all+K_STRIDE, We,be,esrc,offs,wpart, xg_all+2*K_STRIDE);
        dim3 gU(NNODE, 3);
        gru3_k<<<gU,256,0,stream>>>(xg_all, K_STRIDE, xn_all, h, Wx, Wh, bx, bh);
        fc_k<<<gRow,256,0,stream>>>(h, fc_w, fc_b, x_cur, out, p);
    }
}